// Round 6
// baseline (341.341 us; speedup 1.0000x reference)
//
#include <hip/hip_runtime.h>

// x[B][C][H][W] fp32, weight[C][1][H][1], bias[C]
// out[b,c,h,w] = sum_k w_c[k] * x[b,c,(h+k)%56,w] + bias[c]
// Circulant matmul per plane: out = M_c @ x_plane, M_c[h][j] = w_c[(j-h) mod 56],
// padded to 64x64, bf16 MFMA 16x16x32.
// R6: M in LDS with XOR swizzle (T2) -> conflict-free A-frags; B-frags built
// directly from global (X used once per wave -> no LDS staging); LDS 8.4 KB.
#define NB 32
#define NC 384
#define NH 56
#define NW 56
#define HP 64

typedef __attribute__((ext_vector_type(8))) short  bf16x8;
typedef __attribute__((ext_vector_type(4))) float  f32x4;

__device__ __forceinline__ unsigned short f2bf(float f) {
    unsigned u = __float_as_uint(f);                 // RNE float->bf16
    return (unsigned short)((u + 0x7FFFu + ((u >> 16) & 1u)) >> 16);
}

// Block = one c, 4 b-planes (one per wave). grid = NC*8, block = 256.
__global__ __launch_bounds__(256, 3) void gcc_Conv2d_64347200028713_kernel(
    const float* __restrict__ x,
    const float* __restrict__ wgt,
    const float* __restrict__ bias,
    float* __restrict__ out)
{
    const int tid  = threadIdx.x;
    const int lane = tid & 63;
    const int wave = tid >> 6;
    const int c    = blockIdx.x >> 3;       // 0..383
    const int g    = blockIdx.x & 7;        // 0..7
    const int b    = g * 4 + wave;          // 0..31
    const size_t plane = (size_t)(b * NC + c);

    __shared__ float wsh[NH];
    __shared__ __align__(16) unsigned short Mw[HP * HP];   // 8 KB, XOR-swizzled

    // ---- build M_c (swizzled) once per block ----
    if (tid < NH) wsh[tid] = wgt[c * NH + tid];
    __syncthreads();
#pragma unroll
    for (int i = tid; i < HP * HP; i += 256) {
        const int h = i >> 6, j = i & 63;
        unsigned short v = 0;
        if (h < NH && j < NH) { int d = j - h; if (d < 0) d += NH; v = f2bf(wsh[d]); }
        Mw[(h << 6) | (j ^ ((h & 7) << 3))] = v;   // elem-idx XOR swizzle
    }
    __syncthreads();

    const int l15 = lane & 15;              // m / n index within fragment
    const int kg  = lane >> 4;              // k-group 0..3
    const float* __restrict__ xp = x   + plane * (NH * NW);
    float*       __restrict__ op = out + plane * (NH * NW);
    const float bc = bias[c];

    // ---- A-frags: af[ht][kk][e] = M[ht*16+l15][kk*32+kg*8+e] (swizzled read,
    //      2-way banks = free). Rows >=56 are zero -> pad-safe. ----
    bf16x8 af[4][2];
#pragma unroll
    for (int ht = 0; ht < 4; ++ht) {
        const int row = ht * 16 + l15;
#pragma unroll
        for (int kk = 0; kk < 2; ++kk) {
            const int idx = (row << 6) | ((kk * 32 + kg * 8) ^ ((row & 7) << 3));
            af[ht][kk] = *reinterpret_cast<const bf16x8*>(&Mw[idx]);
        }
    }

    // ---- two n-halves (w columns 0..31, 32..55) to cap acc VGPRs ----
#pragma unroll
    for (int half = 0; half < 2; ++half) {
        f32x4 acc[4][2] = {};               // [ht][wtl]
#pragma unroll
        for (int kk = 0; kk < 2; ++kk) {
            int j0 = kk * 32 + kg * 8;      // k-row base for this lane
            if (j0 > 48) j0 = 48;           // kk=1,kg=3: rows 56..63 -> A cols are 0,
                                            // just keep loads in-bounds & finite
            bf16x8 bf[2];
#pragma unroll
            for (int wtl = 0; wtl < 2; ++wtl) {
                int n = (half * 2 + wtl) * 16 + l15;
                if (n > 55) n = 55;         // pad columns: garbage, masked at store
                const float* bp = xp + j0 * NW + n;
#pragma unroll
                for (int e = 0; e < 8; ++e)
                    bf[wtl][e] = (short)f2bf(bp[e * NW]);  // 8 dword loads, imm offs
            }
#pragma unroll
            for (int ht = 0; ht < 4; ++ht) {
#pragma unroll
                for (int wtl = 0; wtl < 2; ++wtl)
                    acc[ht][wtl] = __builtin_amdgcn_mfma_f32_16x16x32_bf16(
                        af[ht][kk], bf[wtl], acc[ht][wtl], 0, 0, 0);
            }
        }
        // ---- store: C/D layout col=lane&15, row=(lane>>4)*4+r (m89) ----
#pragma unroll
        for (int ht = 0; ht < 4; ++ht) {
#pragma unroll
            for (int wtl = 0; wtl < 2; ++wtl) {
                const int ww = (half * 2 + wtl) * 16 + l15;
                if (ww < NW) {
#pragma unroll
                    for (int r = 0; r < 4; ++r) {
                        const int hh = ht * 16 + kg * 4 + r;
                        if (hh < NH)
                            op[hh * NW + ww] = acc[ht][wtl][r] + bc;
                    }
                }
            }
        }
    }
}

extern "C" void kernel_launch(void* const* d_in, const int* in_sizes, int n_in,
                              void* d_out, int out_size, void* d_ws, size_t ws_size,
                              hipStream_t stream)
{
    const float* x    = (const float*)d_in[0];
    const float* wgt  = (const float*)d_in[1];
    const float* bias = (const float*)d_in[2];
    float* out        = (float*)d_out;

    const int grid  = NC * 8;   // 3072 blocks: (c, 8 groups of 4 b-planes)
    const int block = 256;      // 4 waves

    gcc_Conv2d_64347200028713_kernel<<<grid, block, 0, stream>>>(x, wgt, bias, out);
}

// Round 7
// 299.495 us; speedup vs baseline: 1.1397x; 1.1397x over previous
//
#include <hip/hip_runtime.h>

// x[B][C][H][W] fp32, weight[C][1][H][1], bias[C]
// out[b,c,h,w] = sum_k w_c[k] * x[b,c,(h+k)%56,w] + bias[c]
// Circulant matmul per plane: out = M_c @ x_plane, M_c[h][j] = w_c[(j-h) mod 56].
// R7: X staged TRANSPOSED in LDS (Xt[w][j], 144B row stride) via coalesced
// float4 loads + packed b32 writes -> B-frag is ONE ds_read_b128.
// Mw same padded stride -> A-frag ds_read_b128 near conflict-minimum.
#define NB 32
#define NC 384
#define NH 56
#define NW 56
#define HP 64
#define XR 72   // shorts per LDS row = 144 B (64 data + 8 pad); 144%128 != 0

typedef __attribute__((ext_vector_type(8))) short  bf16x8;
typedef __attribute__((ext_vector_type(4))) float  f32x4;
typedef __attribute__((ext_vector_type(4))) unsigned int u32x4;

__device__ __forceinline__ unsigned short f2bf(float f) {
    unsigned u = __float_as_uint(f);                 // RNE float->bf16
    return (unsigned short)((u + 0x7FFFu + ((u >> 16) & 1u)) >> 16);
}

// Block = one c, 4 b-planes (one per wave). grid = NC*8, block = 256.
__global__ __launch_bounds__(256, 3) void gcc_Conv2d_64347200028713_kernel(
    const float* __restrict__ x,
    const float* __restrict__ wgt,
    const float* __restrict__ bias,
    float* __restrict__ out)
{
    const int tid  = threadIdx.x;
    const int lane = tid & 63;
    const int wave = tid >> 6;
    const int c    = blockIdx.x >> 3;
    const int g    = blockIdx.x & 7;
    const int b    = g * 4 + wave;
    const size_t plane = (size_t)(b * NC + c);

    __shared__ float wsh[NH];
    __shared__ __align__(16) unsigned short Mw[HP * XR];          // 9 KB
    __shared__ __align__(16) unsigned short Xt_all[4][HP * XR];   // 36 KB

    const float* __restrict__ xp = x + plane * (NH * NW);

    // ---- issue this wave's global loads FIRST (latency hides under M-build) ----
    const int ls  = (lane < 56) ? lane : 55;
    const int wq  = ls % 14;          // w-quad 0..13
    const int jin = ls / 14;          // 0..3
    float4 va[7], vb[7];
#pragma unroll
    for (int it = 0; it < 7; ++it) {
        const int j0 = it * 8 + jin * 2;               // 0..54, even
        va[it] = *reinterpret_cast<const float4*>(xp + j0 * NW + wq * 4);
        vb[it] = *reinterpret_cast<const float4*>(xp + (j0 + 1) * NW + wq * 4);
    }

    // ---- build M_c (padded-stride rows) ----
    if (tid < NH) wsh[tid] = wgt[c * NH + tid];
    __syncthreads();
#pragma unroll
    for (int i = tid; i < HP * HP; i += 256) {
        const int h = i >> 6, j = i & 63;
        unsigned short v = 0;
        if (h < NH && j < NH) { int d = j - h; if (d < 0) d += NH; v = f2bf(wsh[d]); }
        Mw[h * XR + j] = v;
    }
    __syncthreads();

    // ---- stage Xt[w][j] = x[j][w] (bf16), per-wave private buffer ----
    unsigned short* Xt = Xt_all[wave];
    {   // zero j-pad cols 56..63 for all 64 rows (one b128 per lane)
        u32x4 z = {0u, 0u, 0u, 0u};
        *reinterpret_cast<u32x4*>(&Xt[lane * XR + 56]) = z;
    }
    if (lane < 56) {
#pragma unroll
        for (int it = 0; it < 7; ++it) {
            const int j0 = it * 8 + jin * 2;
#pragma unroll
            for (int i = 0; i < 4; ++i) {
                const float a = (&va[it].x)[i];
                const float bv = (&vb[it].x)[i];
                const unsigned p = (unsigned)f2bf(a) | ((unsigned)f2bf(bv) << 16);
                *reinterpret_cast<unsigned*>(&Xt[(wq * 4 + i) * XR + j0]) = p;
            }
        }
    }
    // rows n=56..63 stay garbage: they feed only output cols >=56 (masked).

    const int l15 = lane & 15;
    const int kg  = lane >> 4;
    const float bc = bias[c];
    float* __restrict__ op = out + plane * (NH * NW);

    // ---- A-frags: af[ht][kk] = M[ht*16+l15][kk*32+kg*8 ..+8] ----
    bf16x8 af[4][2];
#pragma unroll
    for (int ht = 0; ht < 4; ++ht)
#pragma unroll
        for (int kk = 0; kk < 2; ++kk)
            af[ht][kk] = *reinterpret_cast<const bf16x8*>(
                &Mw[(ht * 16 + l15) * XR + kk * 32 + kg * 8]);

    // ---- compute in two n-halves ----
#pragma unroll
    for (int half = 0; half < 2; ++half) {
        f32x4 acc[4][2] = {};
#pragma unroll
        for (int kk = 0; kk < 2; ++kk) {
            bf16x8 bfr[2];
#pragma unroll
            for (int wtl = 0; wtl < 2; ++wtl) {
                const int n = (half * 2 + wtl) * 16 + l15;          // 0..63
                bfr[wtl] = *reinterpret_cast<const bf16x8*>(
                    &Xt[n * XR + kk * 32 + kg * 8]);                // ONE b128
            }
#pragma unroll
            for (int ht = 0; ht < 4; ++ht)
#pragma unroll
                for (int wtl = 0; wtl < 2; ++wtl)
                    acc[ht][wtl] = __builtin_amdgcn_mfma_f32_16x16x32_bf16(
                        af[ht][kk], bfr[wtl], acc[ht][wtl], 0, 0, 0);
        }
        // ---- store (C/D: col=lane&15, row=(lane>>4)*4+r) ----
#pragma unroll
        for (int ht = 0; ht < 4; ++ht)
#pragma unroll
            for (int wtl = 0; wtl < 2; ++wtl) {
                const int ww = (half * 2 + wtl) * 16 + l15;
                if (ww < NW) {
#pragma unroll
                    for (int r = 0; r < 4; ++r) {
                        const int hh = ht * 16 + kg * 4 + r;
                        if (hh < NH)
                            op[hh * NW + ww] = acc[ht][wtl][r] + bc;
                    }
                }
            }
    }
}

extern "C" void kernel_launch(void* const* d_in, const int* in_sizes, int n_in,
                              void* d_out, int out_size, void* d_ws, size_t ws_size,
                              hipStream_t stream)
{
    const float* x    = (const float*)d_in[0];
    const float* wgt  = (const float*)d_in[1];
    const float* bias = (const float*)d_in[2];
    float* out        = (float*)d_out;

    const int grid  = NC * 8;   // 3072 blocks
    const int block = 256;      // 4 waves

    gcc_Conv2d_64347200028713_kernel<<<grid, block, 0, stream>>>(x, wgt, bias, out);
}